// Round 1
// baseline (962.750 us; speedup 1.0000x reference)
//
#include <hip/hip_runtime.h>

typedef unsigned short u16;
typedef unsigned int   u32;
typedef __bf16 bf16_t;
typedef bf16_t bf16x8 __attribute__((ext_vector_type(8)));
typedef float  f32x4  __attribute__((ext_vector_type(4)));

#define DEV static __device__ __forceinline__

// ---- constants ----
// B=4096, L=17, D_MODEL=512, D_INNER=1024, D_STATE=4, DT_RANK=32
// M = B*L = 69632 = 544 * 128
__constant__ int c_HOP[17] = {0,1,4,7,2,5,8,3,6,9,11,14,10,12,15,13,16};
__constant__ int c_BPE[17] = {0,1,2,0,1,2,0,1,2,0,3,4,0,3,4,3,4};
// GRAPH is HOP^-1, so out row for ssm row (b,gl) is b*17 + HOP[gl].

DEV u16 f2bf(float f){
  u32 x = __builtin_bit_cast(u32, f);
  x += 0x7fffu + ((x >> 16) & 1u);        // RNE (no NaN inputs here)
  return (u16)(x >> 16);
}
DEV float bf2f(u32 u){ return __builtin_bit_cast(float, u << 16); }
DEV float silu_f(float v){ return v / (1.f + __expf(-v)); }

DEV void gll16(const void* g, void* l){
  // async global->LDS, 16B per lane; LDS dest is wave-uniform base + lane*16
  __builtin_amdgcn_global_load_lds((__attribute__((address_space(1))) void*)g,
                                   (__attribute__((address_space(3))) void*)l,
                                   16, 0, 0);
}

// ---------------- weight f32 -> bf16 conversion ----------------
__global__ __launch_bounds__(256) void cvt4(
    const float* __restrict__ s0, u16* __restrict__ d0, int n0,
    const float* __restrict__ s1, u16* __restrict__ d1, int n1,
    const float* __restrict__ s2, u16* __restrict__ d2, int n2,
    const float* __restrict__ s3, u16* __restrict__ d3, int n3)
{
  int t = blockIdx.x * 256 + threadIdx.x;
  if (t < n0){ d0[t] = f2bf(s0[t]); return; }
  t -= n0; if (t < n1){ d1[t] = f2bf(s1[t]); return; }
  t -= n1; if (t < n2){ d2[t] = f2bf(s2[t]); return; }
  t -= n2; if (t < n3){ d3[t] = f2bf(s3[t]); }
}

// ---------------- gather + bpe + layernorm -> u (bf16) ----------------
__global__ __launch_bounds__(256) void ln_gather(
    const float* __restrict__ x, const float* __restrict__ bpe,
    const float* __restrict__ lnw, const float* __restrict__ lnb,
    u16* __restrict__ u)
{
  int tok = blockIdx.x;            // b*17 + l
  int b = tok / 17;
  int l = tok - b * 17;
  const float* xr = x   + ((size_t)b * 17 + c_HOP[l]) * 512;
  const float* br = bpe + (size_t)c_BPE[l] * 512;
  int tid = threadIdx.x;
  int d0 = tid * 2;
  float2 xv = *(const float2*)(xr + d0);
  float2 bv = *(const float2*)(br + d0);
  float v0 = xv.x + bv.x, v1 = xv.y + bv.y;

  __shared__ float red[8];
  float s = v0 + v1;
  #pragma unroll
  for (int o = 32; o; o >>= 1) s += __shfl_xor(s, o);
  if ((tid & 63) == 0) red[tid >> 6] = s;
  __syncthreads();
  float mu = (red[0] + red[1] + red[2] + red[3]) * (1.f / 512.f);
  float a0 = v0 - mu, a1 = v1 - mu;
  float q = a0 * a0 + a1 * a1;
  #pragma unroll
  for (int o = 32; o; o >>= 1) q += __shfl_xor(q, o);
  if ((tid & 63) == 0) red[4 + (tid >> 6)] = q;
  __syncthreads();
  float var = (red[4] + red[5] + red[6] + red[7]) * (1.f / 512.f);
  float rs = rsqrtf(var + 1e-5f);

  u16 o0 = f2bf(a0 * rs * lnw[d0]     + lnb[d0]);
  u16 o1 = f2bf(a1 * rs * lnw[d0 + 1] + lnb[d0 + 1]);
  u32 pack = (u32)o0 | ((u32)o1 << 16);
  *(u32*)(u + (size_t)tok * 512 + d0) = pack;
}

// ---------------- MFMA GEMM: C = A(MxK) * W(nW x K)^T ----------------
// 128x128 tile, BK=32, 4 waves (2x2), each wave 64x64 via 4x4 mfma 16x16x32.
// LDS chunk-XOR swizzle: physical chunk p = logical chunk c ^ ((row>>1)&3)
// (applied identically on the pre-swizzled global source and the ds_read).
enum { EPI_SPLIT = 0, EPI_XDBL = 1, EPI_DT = 2, EPI_OUT = 3 };

template<int EPI>
__global__ __launch_bounds__(256) void gemm_bt(
    const u16* __restrict__ A, int lda,
    const u16* __restrict__ W, int nW, int K, int MT,
    u16* __restrict__ ob0, u16* __restrict__ ob1,
    const float* __restrict__ p0, const float* __restrict__ p1,
    const float* __restrict__ xres, float* __restrict__ fout)
{
  __shared__ u16 sA[128 * 32];
  __shared__ u16 sW[128 * 32];
  int bid = blockIdx.x;
  int mt = bid % MT, nt = bid / MT;     // mt fastest: W-tile reused by consecutive blocks
  int brow = mt * 128, bcol = nt * 128;
  int tid = threadIdx.x, lane = tid & 63, wid = tid >> 6;
  int wm = wid >> 1, wn = wid & 1;

  f32x4 acc[4][4] = {};

  int srow = tid >> 2;   // 0..63
  int sch  = tid & 3;    // physical chunk

  for (int kt = 0; kt < K; kt += 32) {
    #pragma unroll
    for (int i = 0; i < 2; i++) {
      int r = i * 64 + srow;
      int c = sch ^ ((r >> 1) & 3);
      gll16(A + (size_t)(brow + r) * lda + kt + c * 8,
            (char*)sA + tid * 16 + i * 4096);
    }
    #pragma unroll
    for (int i = 0; i < 2; i++) {
      int r = i * 64 + srow;
      int wr = bcol + r; wr = (wr < nW) ? wr : 0;   // clamp for ragged N (x_proj)
      int c = sch ^ ((r >> 1) & 3);
      gll16(W + (size_t)wr * K + kt + c * 8,
            (char*)sW + tid * 16 + i * 4096);
    }
    __syncthreads();

    bf16x8 av[4], bv[4];
    #pragma unroll
    for (int mi = 0; mi < 4; mi++) {
      int r = wm * 64 + mi * 16 + (lane & 15);
      int c = (lane >> 4) ^ ((r >> 1) & 3);
      av[mi] = *(const bf16x8*)((const char*)sA + r * 64 + c * 16);
    }
    #pragma unroll
    for (int ni = 0; ni < 4; ni++) {
      int r = wn * 64 + ni * 16 + (lane & 15);
      int c = (lane >> 4) ^ ((r >> 1) & 3);
      bv[ni] = *(const bf16x8*)((const char*)sW + r * 64 + c * 16);
    }
    #pragma unroll
    for (int mi = 0; mi < 4; mi++)
      #pragma unroll
      for (int ni = 0; ni < 4; ni++)
        acc[mi][ni] = __builtin_amdgcn_mfma_f32_16x16x32_bf16(
            av[mi], bv[ni], acc[mi][ni], 0, 0, 0);
    __syncthreads();
  }

  // epilogue: D[row=(lane>>4)*4+r][col=lane&15] per 16x16 fragment
  int r4 = (lane >> 4) * 4;
  int cl = lane & 15;
  #pragma unroll
  for (int mi = 0; mi < 4; mi++) {
    #pragma unroll
    for (int ni = 0; ni < 4; ni++) {
      int col = bcol + wn * 64 + ni * 16 + cl;
      if (col >= nW) continue;
      #pragma unroll
      for (int rr = 0; rr < 4; rr++) {
        int row = brow + wm * 64 + mi * 16 + r4 + rr;
        float v = acc[mi][ni][rr];
        if constexpr (EPI == EPI_SPLIT) {
          // cols [0,1024): xm = silu(v*conv_w+conv_b); [1024,2048): zs = silu(v)
          if (col < 1024) {
            float t = v * p0[col] + p1[col];
            ob0[(size_t)row * 1024 + col] = f2bf(silu_f(t));
          } else {
            ob1[(size_t)row * 1024 + (col - 1024)] = f2bf(silu_f(v));
          }
        } else if constexpr (EPI == EPI_XDBL) {
          ob0[(size_t)row * 40 + col] = f2bf(v);     // col < 40 guaranteed by guard
        } else if constexpr (EPI == EPI_DT) {
          float s = v + p0[col];
          float dtv = (s > 20.f) ? s : log1pf(__expf(s));   // softplus
          ob0[(size_t)row * 1024 + col] = f2bf(dtv);
        } else {  // EPI_OUT: residual add + GRAPH^-1(=HOP) scatter
          u32 rw = (u32)row;
          u32 b = rw / 17u;
          int gl = (int)(rw - b * 17u);
          size_t oi = ((size_t)b * 17 + c_HOP[gl]) * 512 + col;
          fout[oi] = xres[oi] + v;
        }
      }
    }
  }
}

// ---------------- selective scan (one thread per (b,e)) ----------------
__global__ __launch_bounds__(256) void scan_k(
    const u16* __restrict__ xm, const u16* __restrict__ zs,
    const u16* __restrict__ xdbl, u16* __restrict__ dty,
    const float* __restrict__ A_log, const float* __restrict__ Dp)
{
  int gid = blockIdx.x * 256 + threadIdx.x;   // 0 .. 4096*1024-1
  int b = gid >> 10, e = gid & 1023;
  float A0 = -__expf(A_log[e * 4 + 0]);
  float A1 = -__expf(A_log[e * 4 + 1]);
  float A2 = -__expf(A_log[e * 4 + 2]);
  float A3 = -__expf(A_log[e * 4 + 3]);
  float Dv = Dp[e];
  float h0 = 0.f, h1 = 0.f, h2 = 0.f, h3 = 0.f;
  size_t base = (size_t)b * 17;
  for (int t = 0; t < 17; t++) {
    size_t tok = base + t;
    size_t idx = tok * 1024 + e;
    float dt = bf2f(dty[idx]);       // dt written by dt GEMM; overwritten with y below
    float xv = bf2f(xm[idx]);
    float zv = bf2f(zs[idx]);
    uint4 raw = *(const uint4*)(xdbl + tok * 40 + 32);  // B[0..3], C[0..3] bf16
    float B0 = bf2f(raw.x & 0xffffu), B1 = bf2f(raw.x >> 16);
    float B2 = bf2f(raw.y & 0xffffu), B3 = bf2f(raw.y >> 16);
    float C0 = bf2f(raw.z & 0xffffu), C1 = bf2f(raw.z >> 16);
    float C2 = bf2f(raw.w & 0xffffu), C3 = bf2f(raw.w >> 16);
    float dx = dt * xv;
    h0 = __expf(dt * A0) * h0 + dx * B0;
    h1 = __expf(dt * A1) * h1 + dx * B1;
    h2 = __expf(dt * A2) * h2 + dx * B2;
    h3 = __expf(dt * A3) * h3 + dx * B3;
    float y = h0 * C0 + h1 * C1 + h2 * C2 + h3 * C3;
    dty[idx] = f2bf((y + xv * Dv) * zv);   // y_final, in-place over dt
  }
}

// ---------------- launch ----------------
extern "C" void kernel_launch(void* const* d_in, const int* in_sizes, int n_in,
                              void* d_out, int out_size, void* d_ws, size_t ws_size,
                              hipStream_t stream) {
  const float* x     = (const float*)d_in[0];
  const float* bpe   = (const float*)d_in[1];
  const float* lnw   = (const float*)d_in[2];
  const float* lnb   = (const float*)d_in[3];
  const float* w_in  = (const float*)d_in[4];   // (2048, 512)
  const float* convw = (const float*)d_in[5];
  const float* convb = (const float*)d_in[6];
  const float* w_xp  = (const float*)d_in[7];   // (40, 1024)
  const float* w_dt  = (const float*)d_in[8];   // (1024, 32)
  const float* b_dt  = (const float*)d_in[9];
  const float* A_log = (const float*)d_in[10];  // (1024, 4)
  const float* Dp    = (const float*)d_in[11];
  const float* w_out = (const float*)d_in[12];  // (512, 1024)
  float* out = (float*)d_out;

  // workspace layout (u16 elements)
  u16* ws = (u16*)d_ws;
  u16* wb_in  = ws;                       // 2048*512   = 1048576
  u16* wb_out = wb_in  + 1048576;         // 512*1024   = 524288
  u16* wb_xp  = wb_out + 524288;          // 40*1024    = 40960
  u16* wb_dt  = wb_xp  + 40960;           // 1024*32    = 32768
  u16* xm     = wb_dt  + 32768;           // 69632*1024 = 71303168
  u16* zs     = xm     + 71303168;        // 69632*1024
  u16* xdbl   = zs     + 71303168;        // 69632*40   = 2785280
  u16* dty    = xdbl   + 2785280;         // 69632*1024 (dt, then y in-place)
  u16* u      = dty;                      // 69632*512 — u is dead before dty is written
  // total: 218,341,376 u16 = ~437 MB

  const int MT = 544;   // 69632 / 128

  cvt4<<<6432, 256, 0, stream>>>(w_in, wb_in, 1048576, w_out, wb_out, 524288,
                                 w_xp, wb_xp, 40960, w_dt, wb_dt, 32768);

  ln_gather<<<69632, 256, 0, stream>>>(x, bpe, lnw, lnb, u);

  // xz = u @ in_proj^T  -> xm = silu(conv(xm)), zs = silu(z)
  gemm_bt<EPI_SPLIT><<<MT * 16, 256, 0, stream>>>(
      u, 512, wb_in, 2048, 512, MT, xm, zs, convw, convb, nullptr, nullptr);

  // x_dbl = xm @ x_proj^T   (N=40, ragged)
  gemm_bt<EPI_XDBL><<<MT * 1, 256, 0, stream>>>(
      xm, 1024, wb_xp, 40, 1024, MT, xdbl, nullptr, nullptr, nullptr, nullptr, nullptr);

  // dt = softplus(x_dbl[:, :32] @ dt_proj^T + b)
  gemm_bt<EPI_DT><<<MT * 8, 256, 0, stream>>>(
      xdbl, 40, wb_dt, 1024, 32, MT, dty, nullptr, b_dt, nullptr, nullptr, nullptr);

  // selective scan -> y (in place over dt)
  scan_k<<<16384, 256, 0, stream>>>(xm, zs, xdbl, dty, A_log, Dp);

  // out = x + (y @ out_proj^T) scattered through HOP
  gemm_bt<EPI_OUT><<<MT * 4, 256, 0, stream>>>(
      dty, 1024, wb_out, 512, 1024, MT, nullptr, nullptr, nullptr, nullptr, x, out);
}